// Round 21
// baseline (108.174 us; speedup 1.0000x reference)
//
#include <hip/hip_runtime.h>

#define NN 10000
#define NE 320000
#define EPP 5000          // edges per hist partition
#define NPART 64          // NE / EPP

typedef short short8 __attribute__((ext_vector_type(8)));
typedef float f32x4 __attribute__((ext_vector_type(4)));

__device__ __forceinline__ unsigned short f2bf(float f) {
    unsigned u = __float_as_uint(f);
    return (unsigned short)((u + 0x7FFFu + ((u >> 16) & 1u)) >> 16);  // RNE
}
__device__ __forceinline__ float bflo(unsigned v) { return __uint_as_float(v << 16); }
__device__ __forceinline__ float bfhi(unsigned v) { return __uint_as_float(v & 0xffff0000u); }
__device__ __forceinline__ float bf1(unsigned short v) { return __uint_as_float(((unsigned)v) << 16); }

__device__ __forceinline__ int eread(const void* p, int is64, int i) {
    if (is64) return (int)((const long long*)p)[i];
    return ((const int*)p)[i];
}

__device__ __forceinline__ int detect64(const void* ei) {
    const unsigned* idx = (const unsigned*)ei;
    int all0 = 1;
    for (int j = 1; j < 257; j += 2)
        if (idx[j] != 0u) { all0 = 0; break; }
    return all0;   // 1 => int64 (high words of first 128 values all zero)
}

// ---------- pre: xb cast | c-hist | r-hist | W1t cast | wrf fold ----------
__global__ __launch_bounds__(256) void k_pre(const float* __restrict__ x,
                                             unsigned short* __restrict__ xb,
                                             const void* __restrict__ ei,
                                             unsigned short* __restrict__ degp_c,
                                             unsigned short* __restrict__ degp_r,
                                             unsigned* __restrict__ packed_c,
                                             unsigned* __restrict__ packed_r,
                                             const float* __restrict__ W1, const float* __restrict__ a1,
                                             unsigned short* __restrict__ W1t,
                                             float* __restrict__ wrf) {
    __shared__ int sh[NN];                // 40 KB (hist blocks only)
    const int b = blockIdx.x, t = threadIdx.x;
    if (b < 2500) {                       // xb = bf16(x): 640,000 float2 pairs
        const int g = b * 256 + t;
        const float2 v = *(const float2*)&x[(size_t)g * 2];
        ushort2 o; o.x = f2bf(v.x); o.y = f2bf(v.y);
        *(ushort2*)&xb[(size_t)g * 2] = o;
    } else if (b < 2500 + 2 * NPART) {    // LDS histograms, packed (node,rank) out
        const int is64 = detect64(ei);
        const int isC = (b < 2500 + NPART);
        const int p = isC ? (b - 2500) : (b - 2500 - NPART);
        const int ebase = p * EPP;
        for (int q = t; q < NN; q += 256) sh[q] = 0;
        __syncthreads();
        if (isC) {
            for (int q = t; q < EPP; q += 256) {
                const int e = ebase + q;
                const int c = eread(ei, is64, NE + e);
                const unsigned rk = (unsigned)atomicAdd(&sh[c], 1);
                packed_c[e] = ((unsigned)c << 13) | rk;
            }
            __syncthreads();
            for (int q = t; q < NN; q += 256) degp_c[p * NN + q] = (unsigned short)sh[q];
        } else {
            for (int q = t; q < EPP; q += 256) {
                const int e = ebase + q;
                const int r = eread(ei, is64, e);
                const unsigned rk = (unsigned)atomicAdd(&sh[r], 1);
                packed_r[e] = ((unsigned)r << 13) | rk;
            }
            __syncthreads();
            for (int q = t; q < NN; q += 256) degp_r[p * NN + q] = (unsigned short)sh[q];
        }
    } else if (b < 2500 + 2 * NPART + 256) {  // W1t[h][j][k] = bf16(W1[k][h*128+j])
        const int g = (b - 2500 - 2 * NPART) * 256 + t;
        const int h = g >> 14, j = (g >> 7) & 127, k = g & 127;
        W1t[g] = f2bf(W1[(size_t)k * 512 + h * 128 + j]);
    } else {                              // wrf[h*128+k] = W1[k][h-blk] . a1[h][128:]
        const int g = (b - 2500 - 2 * NPART - 256) * 256 + t;
        const int h = g >> 7, k = g & 127;
        const float* wrow = W1 + (size_t)k * 512 + h * 128;
        const float* av = a1 + h * 256 + 128;
        float s = 0.f;
        for (int d = 0; d < 128; d++) s += wrow[d] * av[d];
        wrf[h * 128 + k] = s;
    }
}

// ---------- psum: per-node NPART-partition prefix (u16, [part][node]) + totals ----------
__global__ __launch_bounds__(256) void k_psum(const unsigned short* __restrict__ degp_c,
                                              const unsigned short* __restrict__ degp_r,
                                              unsigned short* __restrict__ pfx_c,
                                              unsigned short* __restrict__ pfx_r,
                                              int* __restrict__ deg_c, int* __restrict__ deg_r) {
    const int g = blockIdx.x * 256 + threadIdx.x;
    if (g >= 2 * NN) return;
    const int arr = g / NN, node = g % NN;
    const unsigned short* degp = arr ? degp_r : degp_c;
    unsigned short* pfx = arr ? pfx_r : pfx_c;
    int* tot = arr ? deg_r : deg_c;
    int sum = 0;
#pragma unroll
    for (int p = 0; p < NPART; p++) {
        pfx[p * NN + node] = (unsigned short)sum;
        sum += (int)degp[p * NN + node];
    }
    tot[node] = sum;
}

// ---------- single-block (1024 thr) exclusive scan of deg_c and deg_r ----------
__device__ void scan_one_1k(const int* __restrict__ deg, int* __restrict__ start, int* ssum) {
    const int t = threadIdx.x;           // 0..1023
    int loc[10];
    const int base = t * 10;
    int sum = 0;
#pragma unroll
    for (int j = 0; j < 10; j++) {
        int i = base + j;
        int v = (i < NN) ? deg[i] : 0;
        loc[j] = sum;
        sum += v;
    }
    const int lane = t & 63, w = t >> 6; // w in 0..15
    int xi = sum;
#pragma unroll
    for (int off = 1; off < 64; off <<= 1) {
        int y = __shfl_up(xi, off);
        if (lane >= off) xi += y;
    }
    __syncthreads();
    if (lane == 63) ssum[w] = xi;
    __syncthreads();
    int woff = 0;
#pragma unroll
    for (int k = 0; k < 16; k++)
        if (k < w) woff += ssum[k];
    const int excl = woff + xi - sum;
#pragma unroll
    for (int j = 0; j < 10; j++) {
        int i = base + j;
        if (i < NN) start[i] = excl + loc[j];
    }
}

__global__ __launch_bounds__(1024) void k_scan2(const int* __restrict__ deg_c, const int* __restrict__ deg_r,
                                                int* __restrict__ start_c, int* __restrict__ start_r) {
    __shared__ int ssum[16];
    scan_one_1k(deg_c, start_c, ssum);
    __syncthreads();
    scan_one_1k(deg_r, start_r, ssum);
}

// ---------- build: 0..1249 dual CSR from packed | 1250..3749 ehr1 from x,wrf ----------
__global__ __launch_bounds__(256) void k_build(const unsigned* __restrict__ packed_c,
                                               const unsigned* __restrict__ packed_r,
                                               const unsigned short* __restrict__ pfx_c,
                                               const unsigned short* __restrict__ pfx_r,
                                               const int* __restrict__ start_c, const int* __restrict__ start_r,
                                               int* __restrict__ csrA, int* __restrict__ csrB,
                                               const float* __restrict__ x, const float* __restrict__ wrf,
                                               float* __restrict__ ehr1) {
    __shared__ float ls[512];
    const int b = blockIdx.x, t = threadIdx.x;
    if (b < 1250) {
        const int e = b * 256 + t;
        const int part = e / EPP;
        const unsigned pc = packed_c[e], pr = packed_r[e];
        const int c = (int)(pc >> 13), rkc = (int)(pc & 8191u);
        const int r = (int)(pr >> 13), rkr = (int)(pr & 8191u);
        csrA[start_c[c] + (int)pfx_c[part * NN + c] + rkc] = r;
        csrB[start_r[r] + (int)pfx_r[part * NN + r] + rkr] = c;
    } else {
        const int lane = t & 63, w = t >> 6;
        ls[t] = wrf[t];
        ls[t + 256] = wrf[t + 256];
        __syncthreads();
        const int i = (b - 1250) * 4 + w;
        const float x0 = x[(size_t)i * 128 + lane];
        const float x1 = x[(size_t)i * 128 + 64 + lane];
        float v[4];
#pragma unroll
        for (int h = 0; h < 4; h++)
            v[h] = x0 * ls[h * 128 + lane] + x1 * ls[h * 128 + 64 + lane];
#pragma unroll
        for (int off = 1; off < 64; off <<= 1) {
#pragma unroll
            for (int j = 0; j < 4; j++) v[j] += __shfl_xor(v[j], off);
        }
        if (lane == 0)
            *(float4*)&ehr1[i * 4] = make_float4(__expf(v[0]), __expf(v[1]), __expf(v[2]), __expf(v[3]));
    }
}

// ---------- rz1: 2 nodes per wave, 32 lanes each ----------
__global__ __launch_bounds__(256) void k_z1(const int* __restrict__ start_r, const int* __restrict__ deg_r,
                                            const int* __restrict__ csrB,
                                            const float* __restrict__ ehr1, float* __restrict__ rz1) {
    const int t = threadIdx.x, lane = t & 63, w = t >> 6;
    const int half = lane >> 5, l32 = lane & 31;
    const int i = blockIdx.x * 8 + w * 2 + half;
    const int s0 = start_r[i], d = deg_r[i];
    float zx = 0.f, zy = 0.f, zz = 0.f, zw = 0.f;
    for (int p = s0 + l32; p < s0 + d; p += 32) {
        const int c = csrB[p];
        const float4 v = *(const float4*)&ehr1[c * 4];
        zx += v.x; zy += v.y; zz += v.z; zw += v.w;
    }
#pragma unroll
    for (int off = 1; off < 32; off <<= 1) {
        zx += __shfl_xor(zx, off); zy += __shfl_xor(zy, off);
        zz += __shfl_xor(zz, off); zw += __shfl_xor(zw, off);
    }
    if (l32 == 0)
        *(float4*)&rz1[i * 4] = make_float4(1.f / zx, 1.f / zy, 1.f / zz, 1.f / zw);
}

// ---------- fused: L1 agg (4 nodes/wave, 16-lane groups, unroll-8) + MFMA + layer-2 GEMM + ehr2 ----------
__global__ __launch_bounds__(256) void k_aggF(const unsigned short* __restrict__ xb,
                                              const float* __restrict__ ehr1, const float* __restrict__ rz1,
                                              const int* __restrict__ start_c, const int* __restrict__ deg_c,
                                              const int* __restrict__ csrA,
                                              const unsigned short* __restrict__ W1t,
                                              const float* __restrict__ W2, const float* __restrict__ a2,
                                              float* __restrict__ h2, float* __restrict__ ehr2) {
    __shared__ unsigned short lx[16 * 512];   // 16 KB: agg tile, fragment-XOR swizzled bf16
    __shared__ float h1f[16 * 128];           //  8 KB: h1m tile (f32)
    const int t = threadIdx.x, lane = t & 63, w = t >> 6;   // 4 waves
    const int n0 = blockIdx.x * 16;

    // ---- Phase A: wave w handles 4 nodes (16-lane groups); lane owns 8 dims; unroll-8 ----
    {
        const int li = lane & 15, g = lane >> 4;
        const int row = w * 4 + g;            // 0..15
        const int i = n0 + row;
        const float4 er4 = *(const float4*)&ehr1[i * 4];
        const int s0 = start_c[i], dg = deg_c[i];
        int m = dg;
        m = max(m, __shfl_xor(m, 16));
        m = max(m, __shfl_xor(m, 32));
        float acc[4][8];
#pragma unroll
        for (int h = 0; h < 4; h++)
#pragma unroll
            for (int d = 0; d < 8; d++) acc[h][d] = 0.f;
        const int niter = (m + 7) >> 3;
        for (int it = 0; it < niter; ++it) {
            const int base = it * 8;
            int rr[8]; uint4 vv[8]; float4 zz[8];
#pragma unroll
            for (int q = 0; q < 8; q++) {
                int p = s0 + base + q;
                if (p >= NE) p = NE - 1;
                rr[q] = csrA[p];
            }
#pragma unroll
            for (int q = 0; q < 8; q++)
                vv[q] = *(const uint4*)&xb[(size_t)rr[q] * 128 + li * 8];
#pragma unroll
            for (int q = 0; q < 8; q++) {
                const float4 z = *(const float4*)&rz1[rr[q] * 4];
                const bool val = (base + q) < dg;
                zz[q] = val ? z : make_float4(0.f, 0.f, 0.f, 0.f);
            }
#pragma unroll
            for (int q = 0; q < 8; q++) {
                float f[8];
                f[0] = bflo(vv[q].x); f[1] = bfhi(vv[q].x);
                f[2] = bflo(vv[q].y); f[3] = bfhi(vv[q].y);
                f[4] = bflo(vv[q].z); f[5] = bfhi(vv[q].z);
                f[6] = bflo(vv[q].w); f[7] = bfhi(vv[q].w);
                const float wz0 = zz[q].x, wz1 = zz[q].y, wz2 = zz[q].z, wz3 = zz[q].w;
#pragma unroll
                for (int d = 0; d < 8; d++) {
                    acc[0][d] += wz0 * f[d];
                    acc[1][d] += wz1 * f[d];
                    acc[2][d] += wz2 * f[d];
                    acc[3][d] += wz3 * f[d];
                }
            }
        }
        const float ef[4] = {er4.x, er4.y, er4.z, er4.w};
#pragma unroll
        for (int h = 0; h < 4; h++) {
            unsigned o[4];
#pragma unroll
            for (int d2 = 0; d2 < 4; d2++) {
                const unsigned lo = f2bf(acc[h][d2 * 2] * ef[h]);
                const unsigned hi = f2bf(acc[h][d2 * 2 + 1] * ef[h]);
                o[d2] = lo | (hi << 16);
            }
            const int f = h * 16 + li;
            const int sc = (f ^ (row & 7)) << 3;
            *(uint4*)&lx[row * 512 + sc] = make_uint4(o[0], o[1], o[2], o[3]);
        }
    }
    __syncthreads();

    // ---- Phase B: 4 waves x 2 col-tiles, MFMA + ELU + head-mean -> h1f LDS ----
    {
        const int r16 = lane & 15, grp = lane >> 4;
#pragma unroll
        for (int jj = 0; jj < 2; jj++) {
            const int j = w * 2 + jj;
            f32x4 hm = (f32x4)0.f;
#pragma unroll
            for (int h = 0; h < 4; h++) {
                f32x4 acc = (f32x4)0.f;
#pragma unroll
                for (int kk = 0; kk < 128; kk += 32) {
                    const int f = h * 16 + (kk >> 3) + grp;
                    const int sc = (f ^ (r16 & 7)) << 3;
                    short8 a = *(const short8*)&lx[r16 * 512 + sc];
                    short8 bfr = *(const short8*)&W1t[(size_t)h * 16384 + (j * 16 + r16) * 128 + kk + grp * 8];
                    acc = __builtin_amdgcn_mfma_f32_16x16x32_bf16(a, bfr, acc, 0, 0, 0);
                }
#pragma unroll
                for (int r = 0; r < 4; r++) {
                    const float v = acc[r];
                    hm[r] += (v > 0.f) ? v : (__expf(v) - 1.f);  // ELU
                }
            }
            // C layout: col = r16, row = grp*4 + r
#pragma unroll
            for (int r = 0; r < 4; r++)
                h1f[(grp * 4 + r) * 128 + j * 16 + r16] = 0.25f * hm[r];
        }
    }
    __syncthreads();

    // ---- Phase C: layer-2 GEMM + ehr2, 4 nodes per wave ----
    {
        const int seg = lane >> 5, c = lane & 31;
#pragma unroll
        for (int q = 0; q < 4; q++) {
            const int nl = w * 4 + q;
            const int i = n0 + nl;
            float part = 0.f;
            if (c < 22) {
                const float* hrow = &h1f[nl * 128 + seg * 64];
                const float* wp = &W2[seg * 64 * 22 + c];
                for (int k = 0; k < 64; k++)
                    part += hrow[k] * wp[k * 22];
            }
            part += __shfl_xor(part, 32);
            if (lane < 22) h2[(size_t)i * 22 + lane] = part;
            float pr = (lane < 22) ? part * a2[22 + lane] : 0.f;
#pragma unroll
            for (int off = 1; off < 64; off <<= 1)
                pr += __shfl_xor(pr, off);
            if (lane == 0) ehr2[i] = __expf(pr);
        }
    }
}

// ---------- z2 + fold: h2s[i][c] = bf16(h2[i][c] / z2[i]), rows padded to 32 ----------
__global__ __launch_bounds__(256) void k_z2s(const int* __restrict__ start_r, const int* __restrict__ deg_r,
                                             const int* __restrict__ csrB,
                                             const float* __restrict__ ehr2, const float* __restrict__ h2,
                                             unsigned short* __restrict__ h2s) {
    const int t = threadIdx.x, lane = t & 63, w = t >> 6;
    const int half = lane >> 5, l32 = lane & 31;
    const int i = blockIdx.x * 8 + w * 2 + half;
    const int s0 = start_r[i], d = deg_r[i];
    float z = 0.f;
    for (int p = s0 + l32; p < s0 + d; p += 32)
        z += ehr2[csrB[p]];
#pragma unroll
    for (int off = 1; off < 32; off <<= 1)
        z += __shfl_xor(z, off);          // all 32 lanes now hold the sum
    const float rz = 1.f / z;
    if (l32 < 22)
        h2s[(size_t)i * 32 + l32] = f2bf(h2[(size_t)i * 22 + l32] * rz);
}

// ---------- L2 aggregation: 2 nodes/wave, 64B-line h2s gather, unroll-8 ----------
__global__ __launch_bounds__(256) void k_agg2(const unsigned short* __restrict__ h2s,
                                              const float* __restrict__ ehr2,
                                              const int* __restrict__ start_c, const int* __restrict__ deg_c,
                                              const int* __restrict__ csrA,
                                              float* __restrict__ out) {
    const int t = threadIdx.x, lane = t & 63, w = t >> 6;
    const int half = lane >> 5, c32 = lane & 31;
    const int i = blockIdx.x * 8 + w * 2 + half;
    const int s0 = start_c[i], dg = deg_c[i];
    const float e2 = ehr2[i];
    const int c = (c32 < 22) ? c32 : 0;
    float acc = 0.f;
    int p = s0;
    const int e8 = s0 + (dg & ~7);
    for (; p < e8; p += 8) {
        int rr[8];
#pragma unroll
        for (int q = 0; q < 8; q++) rr[q] = csrA[p + q];
        float vv[8];
#pragma unroll
        for (int q = 0; q < 8; q++) vv[q] = bf1(h2s[(size_t)rr[q] * 32 + c]);
#pragma unroll
        for (int q = 0; q < 8; q++) acc += vv[q];
    }
    for (; p < s0 + dg; ++p) {
        const int r = csrA[p];
        acc += bf1(h2s[(size_t)r * 32 + c]);
    }
    if (c32 < 22) out[(size_t)i * 22 + c32] = acc * e2;
}

extern "C" void kernel_launch(void* const* d_in, const int* in_sizes, int n_in,
                              void* d_out, int out_size, void* d_ws, size_t ws_size,
                              hipStream_t stream) {
    const float* x  = (const float*)d_in[0];
    const void*  ei = d_in[1];
    const float* W1 = (const float*)d_in[2];
    const float* a1 = (const float*)d_in[3];
    const float* W2 = (const float*)d_in[4];
    const float* a2 = (const float*)d_in[5];
    float* out = (float*)d_out;

    float* ws = (float*)d_ws;
    float* h2   = ws;                                   //   220,000 f
    float* ehr1 = ws + 220000;                          //    40,000 f
    float* rz1  = ws + 260000;                          //    40,000 f
    float* ehr2 = ws + 300000;                          //    10,000 f
    unsigned short* h2s = (unsigned short*)(ws + 310000);   // 320,000 u16 = 160,000 f
    int* deg_c   = (int*)(ws + 470000);
    int* deg_r   = (int*)(ws + 480000);
    int* start_c = (int*)(ws + 490000);
    int* start_r = (int*)(ws + 500000);
    int* csrA    = (int*)(ws + 510000);                 //   320,000
    int* csrB    = (int*)(ws + 830000);                 //   320,000
    float* wrf   = ws + 1150000;                        //       512
    unsigned short* W1t = (unsigned short*)(ws + 1151000);  //  65,536 u16
    unsigned short* xb  = (unsigned short*)(ws + 1184000);  // 1,280,000 u16
    unsigned* packed_c = (unsigned*)(ws + 1824000);     //   320,000 u32
    unsigned* packed_r = (unsigned*)(ws + 2144000);     //   320,000 u32
    unsigned short* degp_c = (unsigned short*)(ws + 2464000);  // 640,000 u16
    unsigned short* degp_r = (unsigned short*)(ws + 2784000);  // 640,000 u16
    unsigned short* pfx_c  = (unsigned short*)(ws + 3104000);  // 640,000 u16 [part][node]
    unsigned short* pfx_r  = (unsigned short*)(ws + 3424000);  // 640,000 u16 [part][node]

    k_pre<<<2500 + 2 * NPART + 258, 256, 0, stream>>>(x, xb, ei, degp_c, degp_r,
                                                      packed_c, packed_r, W1, a1, W1t, wrf);
    k_psum<<<79, 256, 0, stream>>>(degp_c, degp_r, pfx_c, pfx_r, deg_c, deg_r);
    k_scan2<<<1, 1024, 0, stream>>>(deg_c, deg_r, start_c, start_r);
    k_build<<<3750, 256, 0, stream>>>(packed_c, packed_r, pfx_c, pfx_r,
                                      start_c, start_r, csrA, csrB, x, wrf, ehr1);
    k_z1<<<1250, 256, 0, stream>>>(start_r, deg_r, csrB, ehr1, rz1);
    k_aggF<<<625, 256, 0, stream>>>(xb, ehr1, rz1, start_c, deg_c, csrA, W1t,
                                    W2, a2, h2, ehr2);
    k_z2s<<<1250, 256, 0, stream>>>(start_r, deg_r, csrB, ehr2, h2, h2s);
    k_agg2<<<1250, 256, 0, stream>>>(h2s, ehr2, start_c, deg_c, csrA, out);
}

// Round 22
// 99.403 us; speedup vs baseline: 1.0882x; 1.0882x over previous
//
#include <hip/hip_runtime.h>

#define NN 10000
#define NE 320000
#define EPP 5000          // edges per hist partition
#define NPART 64          // NE / EPP

typedef short short8 __attribute__((ext_vector_type(8)));
typedef float f32x4 __attribute__((ext_vector_type(4)));

__device__ __forceinline__ unsigned short f2bf(float f) {
    unsigned u = __float_as_uint(f);
    return (unsigned short)((u + 0x7FFFu + ((u >> 16) & 1u)) >> 16);  // RNE
}
__device__ __forceinline__ float bflo(unsigned v) { return __uint_as_float(v << 16); }
__device__ __forceinline__ float bfhi(unsigned v) { return __uint_as_float(v & 0xffff0000u); }
__device__ __forceinline__ float bf1(unsigned short v) { return __uint_as_float(((unsigned)v) << 16); }

__device__ __forceinline__ int eread(const void* p, int is64, int i) {
    if (is64) return (int)((const long long*)p)[i];
    return ((const int*)p)[i];
}

__device__ __forceinline__ int detect64(const void* ei) {
    const unsigned* idx = (const unsigned*)ei;
    int all0 = 1;
    for (int j = 1; j < 257; j += 2)
        if (idx[j] != 0u) { all0 = 0; break; }
    return all0;   // 1 => int64 (high words of first 128 values all zero)
}

// ---------- pre: xb cast | c-hist | r-hist | W1t cast | wrf fold ----------
__global__ __launch_bounds__(256) void k_pre(const float* __restrict__ x,
                                             unsigned short* __restrict__ xb,
                                             const void* __restrict__ ei,
                                             unsigned short* __restrict__ degp_c,
                                             unsigned short* __restrict__ degp_r,
                                             unsigned* __restrict__ packed_c,
                                             unsigned* __restrict__ packed_r,
                                             const float* __restrict__ W1, const float* __restrict__ a1,
                                             unsigned short* __restrict__ W1t,
                                             float* __restrict__ wrf) {
    __shared__ int sh[NN];                // 40 KB (hist blocks only)
    const int b = blockIdx.x, t = threadIdx.x;
    if (b < 2500) {                       // xb = bf16(x): 640,000 float2 pairs
        const int g = b * 256 + t;
        const float2 v = *(const float2*)&x[(size_t)g * 2];
        ushort2 o; o.x = f2bf(v.x); o.y = f2bf(v.y);
        *(ushort2*)&xb[(size_t)g * 2] = o;
    } else if (b < 2500 + 2 * NPART) {    // LDS histograms, packed (node,rank) out
        const int is64 = detect64(ei);
        const int isC = (b < 2500 + NPART);
        const int p = isC ? (b - 2500) : (b - 2500 - NPART);
        const int ebase = p * EPP;
        for (int q = t; q < NN; q += 256) sh[q] = 0;
        __syncthreads();
        if (isC) {
            for (int q = t; q < EPP; q += 256) {
                const int e = ebase + q;
                const int c = eread(ei, is64, NE + e);
                const unsigned rk = (unsigned)atomicAdd(&sh[c], 1);
                packed_c[e] = ((unsigned)c << 13) | rk;
            }
            __syncthreads();
            for (int q = t; q < NN; q += 256) degp_c[p * NN + q] = (unsigned short)sh[q];
        } else {
            for (int q = t; q < EPP; q += 256) {
                const int e = ebase + q;
                const int r = eread(ei, is64, e);
                const unsigned rk = (unsigned)atomicAdd(&sh[r], 1);
                packed_r[e] = ((unsigned)r << 13) | rk;
            }
            __syncthreads();
            for (int q = t; q < NN; q += 256) degp_r[p * NN + q] = (unsigned short)sh[q];
        }
    } else if (b < 2500 + 2 * NPART + 256) {  // W1t[h][j][k] = bf16(W1[k][h*128+j])
        const int g = (b - 2500 - 2 * NPART) * 256 + t;
        const int h = g >> 14, j = (g >> 7) & 127, k = g & 127;
        W1t[g] = f2bf(W1[(size_t)k * 512 + h * 128 + j]);
    } else {                              // wrf[h*128+k] = W1[k][h-blk] . a1[h][128:]
        const int g = (b - 2500 - 2 * NPART - 256) * 256 + t;
        const int h = g >> 7, k = g & 127;
        const float* wrow = W1 + (size_t)k * 512 + h * 128;
        const float* av = a1 + h * 256 + 128;
        float s = 0.f;
        for (int d = 0; d < 128; d++) s += wrow[d] * av[d];
        wrf[h * 128 + k] = s;
    }
}

// ---------- psum: per-node NPART-partition prefix (u16, [part][node]) + totals ----------
__global__ __launch_bounds__(256) void k_psum(const unsigned short* __restrict__ degp_c,
                                              const unsigned short* __restrict__ degp_r,
                                              unsigned short* __restrict__ pfx_c,
                                              unsigned short* __restrict__ pfx_r,
                                              int* __restrict__ deg_c, int* __restrict__ deg_r) {
    const int g = blockIdx.x * 256 + threadIdx.x;
    if (g >= 2 * NN) return;
    const int arr = g / NN, node = g % NN;
    const unsigned short* degp = arr ? degp_r : degp_c;
    unsigned short* pfx = arr ? pfx_r : pfx_c;
    int* tot = arr ? deg_r : deg_c;
    int sum = 0;
#pragma unroll
    for (int p = 0; p < NPART; p++) {
        pfx[p * NN + node] = (unsigned short)sum;
        sum += (int)degp[p * NN + node];
    }
    tot[node] = sum;
}

// ---------- single-block (1024 thr) exclusive scan of deg_c and deg_r ----------
__device__ void scan_one_1k(const int* __restrict__ deg, int* __restrict__ start, int* ssum) {
    const int t = threadIdx.x;           // 0..1023
    int loc[10];
    const int base = t * 10;
    int sum = 0;
#pragma unroll
    for (int j = 0; j < 10; j++) {
        int i = base + j;
        int v = (i < NN) ? deg[i] : 0;
        loc[j] = sum;
        sum += v;
    }
    const int lane = t & 63, w = t >> 6; // w in 0..15
    int xi = sum;
#pragma unroll
    for (int off = 1; off < 64; off <<= 1) {
        int y = __shfl_up(xi, off);
        if (lane >= off) xi += y;
    }
    __syncthreads();
    if (lane == 63) ssum[w] = xi;
    __syncthreads();
    int woff = 0;
#pragma unroll
    for (int k = 0; k < 16; k++)
        if (k < w) woff += ssum[k];
    const int excl = woff + xi - sum;
#pragma unroll
    for (int j = 0; j < 10; j++) {
        int i = base + j;
        if (i < NN) start[i] = excl + loc[j];
    }
}

__global__ __launch_bounds__(1024) void k_scan2(const int* __restrict__ deg_c, const int* __restrict__ deg_r,
                                                int* __restrict__ start_c, int* __restrict__ start_r) {
    __shared__ int ssum[16];
    scan_one_1k(deg_c, start_c, ssum);
    __syncthreads();
    scan_one_1k(deg_r, start_r, ssum);
}

// ---------- build: 0..1249 dual CSR from packed | 1250..3749 ehr1 from x,wrf ----------
__global__ __launch_bounds__(256) void k_build(const unsigned* __restrict__ packed_c,
                                               const unsigned* __restrict__ packed_r,
                                               const unsigned short* __restrict__ pfx_c,
                                               const unsigned short* __restrict__ pfx_r,
                                               const int* __restrict__ start_c, const int* __restrict__ start_r,
                                               int* __restrict__ csrA, int* __restrict__ csrB,
                                               const float* __restrict__ x, const float* __restrict__ wrf,
                                               float* __restrict__ ehr1) {
    __shared__ float ls[512];
    const int b = blockIdx.x, t = threadIdx.x;
    if (b < 1250) {
        const int e = b * 256 + t;
        const int part = e / EPP;
        const unsigned pc = packed_c[e], pr = packed_r[e];
        const int c = (int)(pc >> 13), rkc = (int)(pc & 8191u);
        const int r = (int)(pr >> 13), rkr = (int)(pr & 8191u);
        csrA[start_c[c] + (int)pfx_c[part * NN + c] + rkc] = r;
        csrB[start_r[r] + (int)pfx_r[part * NN + r] + rkr] = c;
    } else {
        const int lane = t & 63, w = t >> 6;
        ls[t] = wrf[t];
        ls[t + 256] = wrf[t + 256];
        __syncthreads();
        const int i = (b - 1250) * 4 + w;
        const float x0 = x[(size_t)i * 128 + lane];
        const float x1 = x[(size_t)i * 128 + 64 + lane];
        float v[4];
#pragma unroll
        for (int h = 0; h < 4; h++)
            v[h] = x0 * ls[h * 128 + lane] + x1 * ls[h * 128 + 64 + lane];
#pragma unroll
        for (int off = 1; off < 64; off <<= 1) {
#pragma unroll
            for (int j = 0; j < 4; j++) v[j] += __shfl_xor(v[j], off);
        }
        if (lane == 0)
            *(float4*)&ehr1[i * 4] = make_float4(__expf(v[0]), __expf(v[1]), __expf(v[2]), __expf(v[3]));
    }
}

// ---------- rz1: 2 nodes per wave, 32 lanes each ----------
__global__ __launch_bounds__(256) void k_z1(const int* __restrict__ start_r, const int* __restrict__ deg_r,
                                            const int* __restrict__ csrB,
                                            const float* __restrict__ ehr1, float* __restrict__ rz1) {
    const int t = threadIdx.x, lane = t & 63, w = t >> 6;
    const int half = lane >> 5, l32 = lane & 31;
    const int i = blockIdx.x * 8 + w * 2 + half;
    const int s0 = start_r[i], d = deg_r[i];
    float zx = 0.f, zy = 0.f, zz = 0.f, zw = 0.f;
    for (int p = s0 + l32; p < s0 + d; p += 32) {
        const int c = csrB[p];
        const float4 v = *(const float4*)&ehr1[c * 4];
        zx += v.x; zy += v.y; zz += v.z; zw += v.w;
    }
#pragma unroll
    for (int off = 1; off < 32; off <<= 1) {
        zx += __shfl_xor(zx, off); zy += __shfl_xor(zy, off);
        zz += __shfl_xor(zz, off); zw += __shfl_xor(zw, off);
    }
    if (l32 == 0)
        *(float4*)&rz1[i * 4] = make_float4(1.f / zx, 1.f / zy, 1.f / zz, 1.f / zw);
}

// ---------- fused: L1 agg (4 nodes/wave, 16-lane groups) + MFMA + layer-2 GEMM + ehr2 ----------
__global__ __launch_bounds__(256) void k_aggF(const unsigned short* __restrict__ xb,
                                              const float* __restrict__ ehr1, const float* __restrict__ rz1,
                                              const int* __restrict__ start_c, const int* __restrict__ deg_c,
                                              const int* __restrict__ csrA,
                                              const unsigned short* __restrict__ W1t,
                                              const float* __restrict__ W2, const float* __restrict__ a2,
                                              float* __restrict__ h2, float* __restrict__ ehr2) {
    __shared__ unsigned short lx[16 * 512];   // 16 KB: agg tile, fragment-XOR swizzled bf16
    __shared__ float h1f[16 * 128];           //  8 KB: h1m tile (f32)
    const int t = threadIdx.x, lane = t & 63, w = t >> 6;   // 4 waves
    const int n0 = blockIdx.x * 16;

    // ---- Phase A: wave w handles 4 nodes (16-lane groups); lane owns 8 dims ----
    {
        const int li = lane & 15, g = lane >> 4;
        const int row = w * 4 + g;            // 0..15
        const int i = n0 + row;
        const float4 er4 = *(const float4*)&ehr1[i * 4];
        const int s0 = start_c[i], dg = deg_c[i];
        int m = dg;
        m = max(m, __shfl_xor(m, 16));
        m = max(m, __shfl_xor(m, 32));
        float acc[4][8];
#pragma unroll
        for (int h = 0; h < 4; h++)
#pragma unroll
            for (int d = 0; d < 8; d++) acc[h][d] = 0.f;
        const int niter = (m + 3) >> 2;
        for (int it = 0; it < niter; ++it) {
            const int base = it * 4;
            int rr[4]; uint4 vv[4]; float4 zz[4];
#pragma unroll
            for (int q = 0; q < 4; q++) {
                int p = s0 + base + q;
                if (p >= NE) p = NE - 1;
                rr[q] = csrA[p];
            }
#pragma unroll
            for (int q = 0; q < 4; q++)
                vv[q] = *(const uint4*)&xb[(size_t)rr[q] * 128 + li * 8];
#pragma unroll
            for (int q = 0; q < 4; q++) {
                const float4 z = *(const float4*)&rz1[rr[q] * 4];
                const bool val = (base + q) < dg;
                zz[q] = val ? z : make_float4(0.f, 0.f, 0.f, 0.f);
            }
#pragma unroll
            for (int q = 0; q < 4; q++) {
                float f[8];
                f[0] = bflo(vv[q].x); f[1] = bfhi(vv[q].x);
                f[2] = bflo(vv[q].y); f[3] = bfhi(vv[q].y);
                f[4] = bflo(vv[q].z); f[5] = bfhi(vv[q].z);
                f[6] = bflo(vv[q].w); f[7] = bfhi(vv[q].w);
                const float wz0 = zz[q].x, wz1 = zz[q].y, wz2 = zz[q].z, wz3 = zz[q].w;
#pragma unroll
                for (int d = 0; d < 8; d++) {
                    acc[0][d] += wz0 * f[d];
                    acc[1][d] += wz1 * f[d];
                    acc[2][d] += wz2 * f[d];
                    acc[3][d] += wz3 * f[d];
                }
            }
        }
        const float ef[4] = {er4.x, er4.y, er4.z, er4.w};
#pragma unroll
        for (int h = 0; h < 4; h++) {
            unsigned o[4];
#pragma unroll
            for (int d2 = 0; d2 < 4; d2++) {
                const unsigned lo = f2bf(acc[h][d2 * 2] * ef[h]);
                const unsigned hi = f2bf(acc[h][d2 * 2 + 1] * ef[h]);
                o[d2] = lo | (hi << 16);
            }
            const int f = h * 16 + li;
            const int sc = (f ^ (row & 7)) << 3;
            *(uint4*)&lx[row * 512 + sc] = make_uint4(o[0], o[1], o[2], o[3]);
        }
    }
    __syncthreads();

    // ---- Phase B: 4 waves x 2 col-tiles, MFMA + ELU + head-mean -> h1f LDS ----
    {
        const int r16 = lane & 15, grp = lane >> 4;
#pragma unroll
        for (int jj = 0; jj < 2; jj++) {
            const int j = w * 2 + jj;
            f32x4 hm = (f32x4)0.f;
#pragma unroll
            for (int h = 0; h < 4; h++) {
                f32x4 acc = (f32x4)0.f;
#pragma unroll
                for (int kk = 0; kk < 128; kk += 32) {
                    const int f = h * 16 + (kk >> 3) + grp;
                    const int sc = (f ^ (r16 & 7)) << 3;
                    short8 a = *(const short8*)&lx[r16 * 512 + sc];
                    short8 bfr = *(const short8*)&W1t[(size_t)h * 16384 + (j * 16 + r16) * 128 + kk + grp * 8];
                    acc = __builtin_amdgcn_mfma_f32_16x16x32_bf16(a, bfr, acc, 0, 0, 0);
                }
#pragma unroll
                for (int r = 0; r < 4; r++) {
                    const float v = acc[r];
                    hm[r] += (v > 0.f) ? v : (__expf(v) - 1.f);  // ELU
                }
            }
            // C layout: col = r16, row = grp*4 + r
#pragma unroll
            for (int r = 0; r < 4; r++)
                h1f[(grp * 4 + r) * 128 + j * 16 + r16] = 0.25f * hm[r];
        }
    }
    __syncthreads();

    // ---- Phase C: layer-2 GEMM + ehr2, 4 nodes per wave ----
    {
        const int seg = lane >> 5, c = lane & 31;
#pragma unroll
        for (int q = 0; q < 4; q++) {
            const int nl = w * 4 + q;
            const int i = n0 + nl;
            float part = 0.f;
            if (c < 22) {
                const float* hrow = &h1f[nl * 128 + seg * 64];
                const float* wp = &W2[seg * 64 * 22 + c];
                for (int k = 0; k < 64; k++)
                    part += hrow[k] * wp[k * 22];
            }
            part += __shfl_xor(part, 32);
            if (lane < 22) h2[(size_t)i * 22 + lane] = part;
            float pr = (lane < 22) ? part * a2[22 + lane] : 0.f;
#pragma unroll
            for (int off = 1; off < 64; off <<= 1)
                pr += __shfl_xor(pr, off);
            if (lane == 0) ehr2[i] = __expf(pr);
        }
    }
}

// ---------- z2 + fold: h2s[i][c] = bf16(h2[i][c] / z2[i]), rows padded to 32 ----------
__global__ __launch_bounds__(256) void k_z2s(const int* __restrict__ start_r, const int* __restrict__ deg_r,
                                             const int* __restrict__ csrB,
                                             const float* __restrict__ ehr2, const float* __restrict__ h2,
                                             unsigned short* __restrict__ h2s) {
    const int t = threadIdx.x, lane = t & 63, w = t >> 6;
    const int half = lane >> 5, l32 = lane & 31;
    const int i = blockIdx.x * 8 + w * 2 + half;
    const int s0 = start_r[i], d = deg_r[i];
    float z = 0.f;
    for (int p = s0 + l32; p < s0 + d; p += 32)
        z += ehr2[csrB[p]];
#pragma unroll
    for (int off = 1; off < 32; off <<= 1)
        z += __shfl_xor(z, off);          // all 32 lanes now hold the sum
    const float rz = 1.f / z;
    if (l32 < 22)
        h2s[(size_t)i * 32 + l32] = f2bf(h2[(size_t)i * 22 + l32] * rz);
}

// ---------- L2 aggregation: 2 nodes/wave, 64B-line h2s gather, unroll-8 ----------
__global__ __launch_bounds__(256) void k_agg2(const unsigned short* __restrict__ h2s,
                                              const float* __restrict__ ehr2,
                                              const int* __restrict__ start_c, const int* __restrict__ deg_c,
                                              const int* __restrict__ csrA,
                                              float* __restrict__ out) {
    const int t = threadIdx.x, lane = t & 63, w = t >> 6;
    const int half = lane >> 5, c32 = lane & 31;
    const int i = blockIdx.x * 8 + w * 2 + half;
    const int s0 = start_c[i], dg = deg_c[i];
    const float e2 = ehr2[i];
    const int c = (c32 < 22) ? c32 : 0;
    float acc = 0.f;
    int p = s0;
    const int e8 = s0 + (dg & ~7);
    for (; p < e8; p += 8) {
        int rr[8];
#pragma unroll
        for (int q = 0; q < 8; q++) rr[q] = csrA[p + q];
        float vv[8];
#pragma unroll
        for (int q = 0; q < 8; q++) vv[q] = bf1(h2s[(size_t)rr[q] * 32 + c]);
#pragma unroll
        for (int q = 0; q < 8; q++) acc += vv[q];
    }
    for (; p < s0 + dg; ++p) {
        const int r = csrA[p];
        acc += bf1(h2s[(size_t)r * 32 + c]);
    }
    if (c32 < 22) out[(size_t)i * 22 + c32] = acc * e2;
}

extern "C" void kernel_launch(void* const* d_in, const int* in_sizes, int n_in,
                              void* d_out, int out_size, void* d_ws, size_t ws_size,
                              hipStream_t stream) {
    const float* x  = (const float*)d_in[0];
    const void*  ei = d_in[1];
    const float* W1 = (const float*)d_in[2];
    const float* a1 = (const float*)d_in[3];
    const float* W2 = (const float*)d_in[4];
    const float* a2 = (const float*)d_in[5];
    float* out = (float*)d_out;

    float* ws = (float*)d_ws;
    float* h2   = ws;                                   //   220,000 f
    float* ehr1 = ws + 220000;                          //    40,000 f
    float* rz1  = ws + 260000;                          //    40,000 f
    float* ehr2 = ws + 300000;                          //    10,000 f
    unsigned short* h2s = (unsigned short*)(ws + 310000);   // 320,000 u16 = 160,000 f
    int* deg_c   = (int*)(ws + 470000);
    int* deg_r   = (int*)(ws + 480000);
    int* start_c = (int*)(ws + 490000);
    int* start_r = (int*)(ws + 500000);
    int* csrA    = (int*)(ws + 510000);                 //   320,000
    int* csrB    = (int*)(ws + 830000);                 //   320,000
    float* wrf   = ws + 1150000;                        //       512
    unsigned short* W1t = (unsigned short*)(ws + 1151000);  //  65,536 u16
    unsigned short* xb  = (unsigned short*)(ws + 1184000);  // 1,280,000 u16
    unsigned* packed_c = (unsigned*)(ws + 1824000);     //   320,000 u32
    unsigned* packed_r = (unsigned*)(ws + 2144000);     //   320,000 u32
    unsigned short* degp_c = (unsigned short*)(ws + 2464000);  // 640,000 u16
    unsigned short* degp_r = (unsigned short*)(ws + 2784000);  // 640,000 u16
    unsigned short* pfx_c  = (unsigned short*)(ws + 3104000);  // 640,000 u16 [part][node]
    unsigned short* pfx_r  = (unsigned short*)(ws + 3424000);  // 640,000 u16 [part][node]

    k_pre<<<2500 + 2 * NPART + 258, 256, 0, stream>>>(x, xb, ei, degp_c, degp_r,
                                                      packed_c, packed_r, W1, a1, W1t, wrf);
    k_psum<<<79, 256, 0, stream>>>(degp_c, degp_r, pfx_c, pfx_r, deg_c, deg_r);
    k_scan2<<<1, 1024, 0, stream>>>(deg_c, deg_r, start_c, start_r);
    k_build<<<3750, 256, 0, stream>>>(packed_c, packed_r, pfx_c, pfx_r,
                                      start_c, start_r, csrA, csrB, x, wrf, ehr1);
    k_z1<<<1250, 256, 0, stream>>>(start_r, deg_r, csrB, ehr1, rz1);
    k_aggF<<<625, 256, 0, stream>>>(xb, ehr1, rz1, start_c, deg_c, csrA, W1t,
                                    W2, a2, h2, ehr2);
    k_z2s<<<1250, 256, 0, stream>>>(start_r, deg_r, csrB, ehr2, h2, h2s);
    k_agg2<<<1250, 256, 0, stream>>>(h2s, ehr2, start_c, deg_c, csrA, out);
}

// Round 23
// 98.897 us; speedup vs baseline: 1.0938x; 1.0051x over previous
//
#include <hip/hip_runtime.h>

#define NN 10000
#define NE 320000
#define EPP 5000          // edges per hist partition
#define NPART 64          // NE / EPP

typedef short short8 __attribute__((ext_vector_type(8)));
typedef float f32x4 __attribute__((ext_vector_type(4)));

__device__ __forceinline__ unsigned short f2bf(float f) {
    unsigned u = __float_as_uint(f);
    return (unsigned short)((u + 0x7FFFu + ((u >> 16) & 1u)) >> 16);  // RNE
}
__device__ __forceinline__ float bflo(unsigned v) { return __uint_as_float(v << 16); }
__device__ __forceinline__ float bfhi(unsigned v) { return __uint_as_float(v & 0xffff0000u); }
__device__ __forceinline__ float bf1(unsigned short v) { return __uint_as_float(((unsigned)v) << 16); }

__device__ __forceinline__ int eread(const void* p, int is64, int i) {
    if (is64) return (int)((const long long*)p)[i];
    return ((const int*)p)[i];
}

__device__ __forceinline__ int detect64(const void* ei) {
    const unsigned* idx = (const unsigned*)ei;
    int all0 = 1;
    for (int j = 1; j < 257; j += 2)
        if (idx[j] != 0u) { all0 = 0; break; }
    return all0;   // 1 => int64 (high words of first 128 values all zero)
}

// ---------- pre: xb cast | c-hist | r-hist | W1t cast | wrf fold ----------
__global__ __launch_bounds__(256) void k_pre(const float* __restrict__ x,
                                             unsigned short* __restrict__ xb,
                                             const void* __restrict__ ei,
                                             unsigned short* __restrict__ degp_c,
                                             unsigned short* __restrict__ degp_r,
                                             unsigned* __restrict__ packed_c,
                                             unsigned* __restrict__ packed_r,
                                             const float* __restrict__ W1, const float* __restrict__ a1,
                                             unsigned short* __restrict__ W1t,
                                             float* __restrict__ wrf) {
    __shared__ int sh[NN];                // 40 KB (hist blocks only)
    const int b = blockIdx.x, t = threadIdx.x;
    if (b < 2500) {                       // xb = bf16(x): 640,000 float2 pairs
        const int g = b * 256 + t;
        const float2 v = *(const float2*)&x[(size_t)g * 2];
        ushort2 o; o.x = f2bf(v.x); o.y = f2bf(v.y);
        *(ushort2*)&xb[(size_t)g * 2] = o;
    } else if (b < 2500 + 2 * NPART) {    // LDS histograms, packed (node,rank) out
        const int is64 = detect64(ei);
        const int isC = (b < 2500 + NPART);
        const int p = isC ? (b - 2500) : (b - 2500 - NPART);
        const int ebase = p * EPP;
        for (int q = t; q < NN; q += 256) sh[q] = 0;
        __syncthreads();
        if (isC) {
            for (int q = t; q < EPP; q += 256) {
                const int e = ebase + q;
                const int c = eread(ei, is64, NE + e);
                const unsigned rk = (unsigned)atomicAdd(&sh[c], 1);
                packed_c[e] = ((unsigned)c << 13) | rk;
            }
            __syncthreads();
            for (int q = t; q < NN; q += 256) degp_c[p * NN + q] = (unsigned short)sh[q];
        } else {
            for (int q = t; q < EPP; q += 256) {
                const int e = ebase + q;
                const int r = eread(ei, is64, e);
                const unsigned rk = (unsigned)atomicAdd(&sh[r], 1);
                packed_r[e] = ((unsigned)r << 13) | rk;
            }
            __syncthreads();
            for (int q = t; q < NN; q += 256) degp_r[p * NN + q] = (unsigned short)sh[q];
        }
    } else if (b < 2500 + 2 * NPART + 256) {  // W1t[h][j][k] = bf16(W1[k][h*128+j])
        const int g = (b - 2500 - 2 * NPART) * 256 + t;
        const int h = g >> 14, j = (g >> 7) & 127, k = g & 127;
        W1t[g] = f2bf(W1[(size_t)k * 512 + h * 128 + j]);
    } else {                              // wrf[h*128+k] = W1[k][h-blk] . a1[h][128:]
        const int g = (b - 2500 - 2 * NPART - 256) * 256 + t;
        const int h = g >> 7, k = g & 127;
        const float* wrow = W1 + (size_t)k * 512 + h * 128;
        const float* av = a1 + h * 256 + 128;
        float s = 0.f;
        for (int d = 0; d < 128; d++) s += wrow[d] * av[d];
        wrf[h * 128 + k] = s;
    }
}

// ---------- psum: per-node NPART-partition prefix (u16, [part][node]) + totals ----------
__global__ __launch_bounds__(256) void k_psum(const unsigned short* __restrict__ degp_c,
                                              const unsigned short* __restrict__ degp_r,
                                              unsigned short* __restrict__ pfx_c,
                                              unsigned short* __restrict__ pfx_r,
                                              int* __restrict__ deg_c, int* __restrict__ deg_r) {
    const int g = blockIdx.x * 256 + threadIdx.x;
    if (g >= 2 * NN) return;
    const int arr = g / NN, node = g % NN;
    const unsigned short* degp = arr ? degp_r : degp_c;
    unsigned short* pfx = arr ? pfx_r : pfx_c;
    int* tot = arr ? deg_r : deg_c;
    int sum = 0;
#pragma unroll
    for (int p = 0; p < NPART; p++) {
        pfx[p * NN + node] = (unsigned short)sum;
        sum += (int)degp[p * NN + node];
    }
    tot[node] = sum;
}

// ---------- single-block (1024 thr) exclusive scan of deg_c and deg_r ----------
__device__ void scan_one_1k(const int* __restrict__ deg, int* __restrict__ start, int* ssum) {
    const int t = threadIdx.x;           // 0..1023
    int loc[10];
    const int base = t * 10;
    int sum = 0;
#pragma unroll
    for (int j = 0; j < 10; j++) {
        int i = base + j;
        int v = (i < NN) ? deg[i] : 0;
        loc[j] = sum;
        sum += v;
    }
    const int lane = t & 63, w = t >> 6; // w in 0..15
    int xi = sum;
#pragma unroll
    for (int off = 1; off < 64; off <<= 1) {
        int y = __shfl_up(xi, off);
        if (lane >= off) xi += y;
    }
    __syncthreads();
    if (lane == 63) ssum[w] = xi;
    __syncthreads();
    int woff = 0;
#pragma unroll
    for (int k = 0; k < 16; k++)
        if (k < w) woff += ssum[k];
    const int excl = woff + xi - sum;
#pragma unroll
    for (int j = 0; j < 10; j++) {
        int i = base + j;
        if (i < NN) start[i] = excl + loc[j];
    }
}

__global__ __launch_bounds__(1024) void k_scan2(const int* __restrict__ deg_c, const int* __restrict__ deg_r,
                                                int* __restrict__ start_c, int* __restrict__ start_r) {
    __shared__ int ssum[16];
    scan_one_1k(deg_c, start_c, ssum);
    __syncthreads();
    scan_one_1k(deg_r, start_r, ssum);
}

// ---------- build: 0..1249 dual CSR from packed | 1250..3749 ehr1 from x,wrf ----------
__global__ __launch_bounds__(256) void k_build(const unsigned* __restrict__ packed_c,
                                               const unsigned* __restrict__ packed_r,
                                               const unsigned short* __restrict__ pfx_c,
                                               const unsigned short* __restrict__ pfx_r,
                                               const int* __restrict__ start_c, const int* __restrict__ start_r,
                                               int* __restrict__ csrA, int* __restrict__ csrB,
                                               const float* __restrict__ x, const float* __restrict__ wrf,
                                               float* __restrict__ ehr1) {
    __shared__ float ls[512];
    const int b = blockIdx.x, t = threadIdx.x;
    if (b < 1250) {
        const int e = b * 256 + t;
        const int part = e / EPP;
        const unsigned pc = packed_c[e], pr = packed_r[e];
        const int c = (int)(pc >> 13), rkc = (int)(pc & 8191u);
        const int r = (int)(pr >> 13), rkr = (int)(pr & 8191u);
        csrA[start_c[c] + (int)pfx_c[part * NN + c] + rkc] = r;
        csrB[start_r[r] + (int)pfx_r[part * NN + r] + rkr] = c;
    } else {
        const int lane = t & 63, w = t >> 6;
        ls[t] = wrf[t];
        ls[t + 256] = wrf[t + 256];
        __syncthreads();
        const int i = (b - 1250) * 4 + w;
        const float x0 = x[(size_t)i * 128 + lane];
        const float x1 = x[(size_t)i * 128 + 64 + lane];
        float v[4];
#pragma unroll
        for (int h = 0; h < 4; h++)
            v[h] = x0 * ls[h * 128 + lane] + x1 * ls[h * 128 + 64 + lane];
#pragma unroll
        for (int off = 1; off < 64; off <<= 1) {
#pragma unroll
            for (int j = 0; j < 4; j++) v[j] += __shfl_xor(v[j], off);
        }
        if (lane == 0)
            *(float4*)&ehr1[i * 4] = make_float4(__expf(v[0]), __expf(v[1]), __expf(v[2]), __expf(v[3]));
    }
}

// ---------- rz1: 2 nodes per wave, 32 lanes each ----------
__global__ __launch_bounds__(256) void k_z1(const int* __restrict__ start_r, const int* __restrict__ deg_r,
                                            const int* __restrict__ csrB,
                                            const float* __restrict__ ehr1, float* __restrict__ rz1) {
    const int t = threadIdx.x, lane = t & 63, w = t >> 6;
    const int half = lane >> 5, l32 = lane & 31;
    const int i = blockIdx.x * 8 + w * 2 + half;
    const int s0 = start_r[i], d = deg_r[i];
    float zx = 0.f, zy = 0.f, zz = 0.f, zw = 0.f;
    for (int p = s0 + l32; p < s0 + d; p += 32) {
        const int c = csrB[p];
        const float4 v = *(const float4*)&ehr1[c * 4];
        zx += v.x; zy += v.y; zz += v.z; zw += v.w;
    }
#pragma unroll
    for (int off = 1; off < 32; off <<= 1) {
        zx += __shfl_xor(zx, off); zy += __shfl_xor(zy, off);
        zz += __shfl_xor(zz, off); zw += __shfl_xor(zw, off);
    }
    if (l32 == 0)
        *(float4*)&rz1[i * 4] = make_float4(1.f / zx, 1.f / zy, 1.f / zz, 1.f / zw);
}

// ---------- fused: L1 agg (4 nodes/wave, 16-lane groups) + MFMA + layer-2 GEMM + ehr2 ----------
__global__ __launch_bounds__(256) void k_aggF(const unsigned short* __restrict__ xb,
                                              const float* __restrict__ ehr1, const float* __restrict__ rz1,
                                              const int* __restrict__ start_c, const int* __restrict__ deg_c,
                                              const int* __restrict__ csrA,
                                              const unsigned short* __restrict__ W1t,
                                              const float* __restrict__ W2, const float* __restrict__ a2,
                                              float* __restrict__ h2, float* __restrict__ ehr2) {
    __shared__ unsigned short lx[16 * 512];   // 16 KB: agg tile, fragment-XOR swizzled bf16
    __shared__ float h1f[16 * 128];           //  8 KB: h1m tile (f32)
    const int t = threadIdx.x, lane = t & 63, w = t >> 6;   // 4 waves
    const int n0 = blockIdx.x * 16;

    // ---- Phase A: wave w handles 4 nodes (16-lane groups); lane owns 8 dims ----
    {
        const int li = lane & 15, g = lane >> 4;
        const int row = w * 4 + g;            // 0..15
        const int i = n0 + row;
        const float4 er4 = *(const float4*)&ehr1[i * 4];
        const int s0 = start_c[i], dg = deg_c[i];
        int m = dg;
        m = max(m, __shfl_xor(m, 16));
        m = max(m, __shfl_xor(m, 32));
        float acc[4][8];
#pragma unroll
        for (int h = 0; h < 4; h++)
#pragma unroll
            for (int d = 0; d < 8; d++) acc[h][d] = 0.f;
        const int niter = (m + 3) >> 2;
        for (int it = 0; it < niter; ++it) {
            const int base = it * 4;
            int rr[4]; uint4 vv[4]; float4 zz[4];
#pragma unroll
            for (int q = 0; q < 4; q++) {
                int p = s0 + base + q;
                if (p >= NE) p = NE - 1;
                rr[q] = csrA[p];
            }
#pragma unroll
            for (int q = 0; q < 4; q++)
                vv[q] = *(const uint4*)&xb[(size_t)rr[q] * 128 + li * 8];
#pragma unroll
            for (int q = 0; q < 4; q++) {
                const float4 z = *(const float4*)&rz1[rr[q] * 4];
                const bool val = (base + q) < dg;
                zz[q] = val ? z : make_float4(0.f, 0.f, 0.f, 0.f);
            }
#pragma unroll
            for (int q = 0; q < 4; q++) {
                float f[8];
                f[0] = bflo(vv[q].x); f[1] = bfhi(vv[q].x);
                f[2] = bflo(vv[q].y); f[3] = bfhi(vv[q].y);
                f[4] = bflo(vv[q].z); f[5] = bfhi(vv[q].z);
                f[6] = bflo(vv[q].w); f[7] = bfhi(vv[q].w);
                const float wz0 = zz[q].x, wz1 = zz[q].y, wz2 = zz[q].z, wz3 = zz[q].w;
#pragma unroll
                for (int d = 0; d < 8; d++) {
                    acc[0][d] += wz0 * f[d];
                    acc[1][d] += wz1 * f[d];
                    acc[2][d] += wz2 * f[d];
                    acc[3][d] += wz3 * f[d];
                }
            }
        }
        const float ef[4] = {er4.x, er4.y, er4.z, er4.w};
#pragma unroll
        for (int h = 0; h < 4; h++) {
            unsigned o[4];
#pragma unroll
            for (int d2 = 0; d2 < 4; d2++) {
                const unsigned lo = f2bf(acc[h][d2 * 2] * ef[h]);
                const unsigned hi = f2bf(acc[h][d2 * 2 + 1] * ef[h]);
                o[d2] = lo | (hi << 16);
            }
            const int f = h * 16 + li;
            const int sc = (f ^ (row & 7)) << 3;
            *(uint4*)&lx[row * 512 + sc] = make_uint4(o[0], o[1], o[2], o[3]);
        }
    }
    __syncthreads();

    // ---- Phase B: 4 waves x 2 col-tiles, MFMA + ELU + head-mean -> h1f LDS ----
    {
        const int r16 = lane & 15, grp = lane >> 4;
#pragma unroll
        for (int jj = 0; jj < 2; jj++) {
            const int j = w * 2 + jj;
            f32x4 hm = (f32x4)0.f;
#pragma unroll
            for (int h = 0; h < 4; h++) {
                f32x4 acc = (f32x4)0.f;
#pragma unroll
                for (int kk = 0; kk < 128; kk += 32) {
                    const int f = h * 16 + (kk >> 3) + grp;
                    const int sc = (f ^ (r16 & 7)) << 3;
                    short8 a = *(const short8*)&lx[r16 * 512 + sc];
                    short8 bfr = *(const short8*)&W1t[(size_t)h * 16384 + (j * 16 + r16) * 128 + kk + grp * 8];
                    acc = __builtin_amdgcn_mfma_f32_16x16x32_bf16(a, bfr, acc, 0, 0, 0);
                }
#pragma unroll
                for (int r = 0; r < 4; r++) {
                    const float v = acc[r];
                    hm[r] += (v > 0.f) ? v : (__expf(v) - 1.f);  // ELU
                }
            }
            // C layout: col = r16, row = grp*4 + r
#pragma unroll
            for (int r = 0; r < 4; r++)
                h1f[(grp * 4 + r) * 128 + j * 16 + r16] = 0.25f * hm[r];
        }
    }
    __syncthreads();

    // ---- Phase C: layer-2 GEMM + ehr2, 4 nodes per wave; 4-way ILP k-loop ----
    {
        const int seg = lane >> 5, c = lane & 31;
#pragma unroll
        for (int q = 0; q < 4; q++) {
            const int nl = w * 4 + q;
            const int i = n0 + nl;
            float part = 0.f;
            if (c < 22) {
                const float* hrow = &h1f[nl * 128 + seg * 64];
                const float* wp = &W2[seg * 64 * 22 + c];
                float pp0 = 0.f, pp1 = 0.f, pp2 = 0.f, pp3 = 0.f;
#pragma unroll
                for (int k = 0; k < 64; k += 4) {
                    pp0 += hrow[k]     * wp[k * 22];
                    pp1 += hrow[k + 1] * wp[(k + 1) * 22];
                    pp2 += hrow[k + 2] * wp[(k + 2) * 22];
                    pp3 += hrow[k + 3] * wp[(k + 3) * 22];
                }
                part = (pp0 + pp1) + (pp2 + pp3);
            }
            part += __shfl_xor(part, 32);
            if (lane < 22) h2[(size_t)i * 22 + lane] = part;
            float pr = (lane < 22) ? part * a2[22 + lane] : 0.f;
#pragma unroll
            for (int off = 1; off < 64; off <<= 1)
                pr += __shfl_xor(pr, off);
            if (lane == 0) ehr2[i] = __expf(pr);
        }
    }
}

// ---------- z2 + fold: h2s[i][c] = bf16(h2[i][c] / z2[i]), rows padded to 32 ----------
__global__ __launch_bounds__(256) void k_z2s(const int* __restrict__ start_r, const int* __restrict__ deg_r,
                                             const int* __restrict__ csrB,
                                             const float* __restrict__ ehr2, const float* __restrict__ h2,
                                             unsigned short* __restrict__ h2s) {
    const int t = threadIdx.x, lane = t & 63, w = t >> 6;
    const int half = lane >> 5, l32 = lane & 31;
    const int i = blockIdx.x * 8 + w * 2 + half;
    const int s0 = start_r[i], d = deg_r[i];
    float z = 0.f;
    for (int p = s0 + l32; p < s0 + d; p += 32)
        z += ehr2[csrB[p]];
#pragma unroll
    for (int off = 1; off < 32; off <<= 1)
        z += __shfl_xor(z, off);          // all 32 lanes now hold the sum
    const float rz = 1.f / z;
    if (l32 < 22)
        h2s[(size_t)i * 32 + l32] = f2bf(h2[(size_t)i * 22 + l32] * rz);
}

// ---------- L2 aggregation: 2 nodes/wave, 64B-line h2s gather, unroll-8 ----------
__global__ __launch_bounds__(256) void k_agg2(const unsigned short* __restrict__ h2s,
                                              const float* __restrict__ ehr2,
                                              const int* __restrict__ start_c, const int* __restrict__ deg_c,
                                              const int* __restrict__ csrA,
                                              float* __restrict__ out) {
    const int t = threadIdx.x, lane = t & 63, w = t >> 6;
    const int half = lane >> 5, c32 = lane & 31;
    const int i = blockIdx.x * 8 + w * 2 + half;
    const int s0 = start_c[i], dg = deg_c[i];
    const float e2 = ehr2[i];
    const int c = (c32 < 22) ? c32 : 0;
    float acc = 0.f;
    int p = s0;
    const int e8 = s0 + (dg & ~7);
    for (; p < e8; p += 8) {
        int rr[8];
#pragma unroll
        for (int q = 0; q < 8; q++) rr[q] = csrA[p + q];
        float vv[8];
#pragma unroll
        for (int q = 0; q < 8; q++) vv[q] = bf1(h2s[(size_t)rr[q] * 32 + c]);
#pragma unroll
        for (int q = 0; q < 8; q++) acc += vv[q];
    }
    for (; p < s0 + dg; ++p) {
        const int r = csrA[p];
        acc += bf1(h2s[(size_t)r * 32 + c]);
    }
    if (c32 < 22) out[(size_t)i * 22 + c32] = acc * e2;
}

extern "C" void kernel_launch(void* const* d_in, const int* in_sizes, int n_in,
                              void* d_out, int out_size, void* d_ws, size_t ws_size,
                              hipStream_t stream) {
    const float* x  = (const float*)d_in[0];
    const void*  ei = d_in[1];
    const float* W1 = (const float*)d_in[2];
    const float* a1 = (const float*)d_in[3];
    const float* W2 = (const float*)d_in[4];
    const float* a2 = (const float*)d_in[5];
    float* out = (float*)d_out;

    float* ws = (float*)d_ws;
    float* h2   = ws;                                   //   220,000 f
    float* ehr1 = ws + 220000;                          //    40,000 f
    float* rz1  = ws + 260000;                          //    40,000 f
    float* ehr2 = ws + 300000;                          //    10,000 f
    unsigned short* h2s = (unsigned short*)(ws + 310000);   // 320,000 u16 = 160,000 f
    int* deg_c   = (int*)(ws + 470000);
    int* deg_r   = (int*)(ws + 480000);
    int* start_c = (int*)(ws + 490000);
    int* start_r = (int*)(ws + 500000);
    int* csrA    = (int*)(ws + 510000);                 //   320,000
    int* csrB    = (int*)(ws + 830000);                 //   320,000
    float* wrf   = ws + 1150000;                        //       512
    unsigned short* W1t = (unsigned short*)(ws + 1151000);  //  65,536 u16
    unsigned short* xb  = (unsigned short*)(ws + 1184000);  // 1,280,000 u16
    unsigned* packed_c = (unsigned*)(ws + 1824000);     //   320,000 u32
    unsigned* packed_r = (unsigned*)(ws + 2144000);     //   320,000 u32
    unsigned short* degp_c = (unsigned short*)(ws + 2464000);  // 640,000 u16
    unsigned short* degp_r = (unsigned short*)(ws + 2784000);  // 640,000 u16
    unsigned short* pfx_c  = (unsigned short*)(ws + 3104000);  // 640,000 u16 [part][node]
    unsigned short* pfx_r  = (unsigned short*)(ws + 3424000);  // 640,000 u16 [part][node]

    k_pre<<<2500 + 2 * NPART + 258, 256, 0, stream>>>(x, xb, ei, degp_c, degp_r,
                                                      packed_c, packed_r, W1, a1, W1t, wrf);
    k_psum<<<79, 256, 0, stream>>>(degp_c, degp_r, pfx_c, pfx_r, deg_c, deg_r);
    k_scan2<<<1, 1024, 0, stream>>>(deg_c, deg_r, start_c, start_r);
    k_build<<<3750, 256, 0, stream>>>(packed_c, packed_r, pfx_c, pfx_r,
                                      start_c, start_r, csrA, csrB, x, wrf, ehr1);
    k_z1<<<1250, 256, 0, stream>>>(start_r, deg_r, csrB, ehr1, rz1);
    k_aggF<<<625, 256, 0, stream>>>(xb, ehr1, rz1, start_c, deg_c, csrA, W1t,
                                    W2, a2, h2, ehr2);
    k_z2s<<<1250, 256, 0, stream>>>(start_r, deg_r, csrB, ehr2, h2, h2s);
    k_agg2<<<1250, 256, 0, stream>>>(h2s, ehr2, start_c, deg_c, csrA, out);
}